// Round 1
// baseline (780.476 us; speedup 1.0000x reference)
//
#include <hip/hip_runtime.h>

#define NB 64   // batch segments
#define NC 32   // channels

// Order-preserving float -> uint map so integer atomicMax == float max.
__device__ __forceinline__ unsigned f2ord(float f) {
    unsigned u = __float_as_uint(f);
    return (u & 0x80000000u) ? ~u : (u | 0x80000000u);
}
__device__ __forceinline__ float ord2f(unsigned k) {
    return __uint_as_float((k & 0x80000000u) ? (k & 0x7fffffffu) : ~k);
}

// ---------------------------------------------------------------------------
// Kernel 1: segment max over sorted batch_ids. [N,32] fp32 -> gkeys[64*32] u32
// Block = 256 threads, owns `ppb` contiguous points. Lane layout: s = t>>3
// (point slot 0..31), q = t&7 (float4 quad 0..7) -> wave reads contiguous 1KiB.
// ---------------------------------------------------------------------------
__global__ __launch_bounds__(256) void segmax_kernel(
    const float* __restrict__ feat, const int* __restrict__ bids,
    unsigned* __restrict__ gkeys, int n, int ppb)
{
    __shared__ unsigned table[NB * NC];
    const int t = threadIdx.x;
    for (int i = t; i < NB * NC; i += 256) table[i] = 0u;
    __syncthreads();

    const int p0 = blockIdx.x * ppb;
    if (p0 >= n) return;
    const int p1 = min(n, p0 + ppb);
    const int s = t >> 3;
    const int q = t & 7;

    float4 vmax = make_float4(-3.402823466e38f, -3.402823466e38f,
                              -3.402823466e38f, -3.402823466e38f);
    int cur = -1;
    const float4* fp = reinterpret_cast<const float4*>(feat) + (size_t)(p0 + s) * 8 + q;

    for (int p = p0 + s; p < p1; p += 32, fp += 256) {
        int bid = bids[p];
        if (bid != cur) {
            if (cur >= 0) {
                unsigned* e = &table[cur * NC + q * 4];
                atomicMax(&e[0], f2ord(vmax.x));
                atomicMax(&e[1], f2ord(vmax.y));
                atomicMax(&e[2], f2ord(vmax.z));
                atomicMax(&e[3], f2ord(vmax.w));
            }
            vmax = make_float4(-3.402823466e38f, -3.402823466e38f,
                               -3.402823466e38f, -3.402823466e38f);
            cur = bid;
        }
        float4 v = *fp;
        vmax.x = fmaxf(vmax.x, v.x);
        vmax.y = fmaxf(vmax.y, v.y);
        vmax.z = fmaxf(vmax.z, v.z);
        vmax.w = fmaxf(vmax.w, v.w);
    }
    if (cur >= 0) {
        unsigned* e = &table[cur * NC + q * 4];
        atomicMax(&e[0], f2ord(vmax.x));
        atomicMax(&e[1], f2ord(vmax.y));
        atomicMax(&e[2], f2ord(vmax.z));
        atomicMax(&e[3], f2ord(vmax.w));
    }
    __syncthreads();

    // Flush only the ids this block actually touched (sorted ids -> range).
    const int first = bids[p0];
    const int last  = bids[p1 - 1];
    const int cnt   = (last - first + 1) * NC;
    for (int e = t; e < cnt; e += 256) {
        int idx = first * NC + e;
        unsigned k = table[idx];
        if (k) atomicMax(&gkeys[idx], k);
    }
}

// ---------------------------------------------------------------------------
// Kernel 2: g[64,32] -> h1=relu(g@W1+b1)[64,256] -> h2=relu(h1@W2+b2)[64,512]
// One block per batch row. h1 kept in LDS; h2 written to global ws.
// ---------------------------------------------------------------------------
__global__ __launch_bounds__(256) void mlp12_kernel(
    const unsigned* __restrict__ gkeys,
    const float* __restrict__ W1, const float* __restrict__ b1,
    const float* __restrict__ W2, const float* __restrict__ b2,
    float* __restrict__ h2out)
{
    __shared__ float gs[NC];
    __shared__ float h1s[256];
    const int b = blockIdx.x;
    const int t = threadIdx.x;

    if (t < NC) {
        unsigned k = gkeys[b * NC + t];
        gs[t] = k ? ord2f(k) : 0.0f;   // empty segment (-inf) -> 0 like ref
    }
    __syncthreads();

    float acc = b1[t];
    #pragma unroll
    for (int k = 0; k < NC; ++k) acc += gs[k] * W1[k * 256 + t];
    h1s[t] = fmaxf(acc, 0.0f);
    __syncthreads();

    float a0 = b2[t];
    float a1 = b2[t + 256];
    for (int k = 0; k < 256; ++k) {
        float h = h1s[k];
        a0 += h * W2[k * 512 + t];
        a1 += h * W2[k * 512 + t + 256];
    }
    h2out[b * 512 + t]       = fmaxf(a0, 0.0f);
    h2out[b * 512 + t + 256] = fmaxf(a1, 0.0f);
}

// ---------------------------------------------------------------------------
// Kernel 3: out = h2 @ W3 + b3, [64,512]x[512,3072] -> [64,3072]
// Grid = 8 rowgroups x 12 colchunks = 96 blocks. Thread owns 8 rows x 1 col.
// W3 loads coalesced over threads; h2 operands wave-uniform (scalar path).
// ---------------------------------------------------------------------------
__global__ __launch_bounds__(256) void mlp3_kernel(
    const float* __restrict__ h2, const float* __restrict__ W3,
    const float* __restrict__ b3, float* __restrict__ out)
{
    const int rg = blockIdx.x / 12;          // 0..7
    const int cc = blockIdx.x % 12;          // 0..11
    const int t  = threadIdx.x;
    const int c  = cc * 256 + t;             // 0..3071
    const int r0 = rg * 8;

    float acc[8];
    const float bias = b3[c];
    #pragma unroll
    for (int i = 0; i < 8; ++i) acc[i] = bias;

    #pragma unroll 4
    for (int k = 0; k < 512; ++k) {
        float w = W3[(size_t)k * 3072 + c];
        #pragma unroll
        for (int i = 0; i < 8; ++i)
            acc[i] += h2[(r0 + i) * 512 + k] * w;
    }
    #pragma unroll
    for (int i = 0; i < 8; ++i)
        out[(size_t)(r0 + i) * 3072 + c] = acc[i];
}

extern "C" void kernel_launch(void* const* d_in, const int* in_sizes, int n_in,
                              void* d_out, int out_size, void* d_ws, size_t ws_size,
                              hipStream_t stream) {
    const float* feat = (const float*)d_in[0];   // [N,32]
    const int*   bids = (const int*)d_in[1];     // [N]
    const float* W1   = (const float*)d_in[2];   // [32,256]
    const float* b1   = (const float*)d_in[3];   // [256]
    const float* W2   = (const float*)d_in[4];   // [256,512]
    const float* b2   = (const float*)d_in[5];   // [512]
    const float* W3   = (const float*)d_in[6];   // [512,3072]
    const float* b3   = (const float*)d_in[7];   // [3072]
    float* out = (float*)d_out;

    unsigned* gkeys = (unsigned*)d_ws;                       // 64*32 u32 = 8KB
    float*    h2buf = (float*)((char*)d_ws + 8192);          // 64*512 f32 = 128KB

    const int n = in_sizes[1];
    hipMemsetAsync(gkeys, 0, NB * NC * sizeof(unsigned), stream);

    const int PPB = 2048;
    const int nblocks = (n + PPB - 1) / PPB;
    segmax_kernel<<<nblocks, 256, 0, stream>>>(feat, bids, gkeys, n, PPB);
    mlp12_kernel<<<NB, 256, 0, stream>>>(gkeys, W1, b1, W2, b2, h2buf);
    mlp3_kernel<<<96, 256, 0, stream>>>(h2buf, W3, b3, out);
}